// Round 3
// baseline (540.562 us; speedup 1.0000x reference)
//
#include <hip/hip_runtime.h>
#include <math.h>

// B=8, T=2048, D=768. out[b,i,:768] = masked softmax attn (denominator over ALL
// causal j; sit-mask zeroes numerator only; row gated by mask_i), out[b,i,768:] = x[b,i].
//
// v6: direct-to-register K/V (no K/V LDS staging at all — each wave consumed
// only its own staged chunk, so LDS sharing was zero). 512-thread blocks,
// 8 waves x 96-d chunks -> 2 blocks/CU x 16 waves = 50% occupancy ceiling.
// K(t+1)/V(t+1) register prefetch issued right after consumption at t;
// lds_barrier (no vmcnt drain) keeps them in flight across barriers.
// v5 split-K LPT mapping, prep, and combine kernels verbatim.
constexpr int kT = 2048;
constexpr int kD = 768;
constexpr int kTileShorts = 16 * kD;       // 12288 shorts per 16-row tile
constexpr int kTilesPerBatch = kT / 16;    // 128

typedef __attribute__((ext_vector_type(8))) short short8;
typedef __attribute__((ext_vector_type(4))) float f32x4;
typedef __attribute__((ext_vector_type(16))) float f32x16;

#define FB(f) __builtin_bit_cast(unsigned, (f))
__device__ __forceinline__ unsigned pk_hi16(unsigned hi, unsigned lo) {
  return __builtin_amdgcn_perm(hi, lo, 0x07060302);  // bf16 truncation pack
}
__device__ __forceinline__ unsigned pk_lo16(unsigned hi, unsigned lo) {
  return __builtin_amdgcn_perm(hi, lo, 0x05040100);
}

// Workgroup barrier WITHOUT the vmcnt(0) drain __syncthreads() emits.
// lgkmcnt(0) makes LDS writes visible; global register loads stay in flight
// (consumers get compiler-inserted vmcnt waits at use).
__device__ __forceinline__ void lds_barrier() {
  asm volatile("" ::: "memory");
  __builtin_amdgcn_s_waitcnt(0xC07F);   // vmcnt=63, expcnt=7, lgkmcnt=0
  __builtin_amdgcn_s_barrier();
  asm volatile("" ::: "memory");
}

// Direct global->LDS copy, 16B/lane. LDS dest = wave-uniform base + lane*16.
__device__ __forceinline__ void gload_lds16(const void* g, void* l) {
  __builtin_amdgcn_global_load_lds(
      (const __attribute__((address_space(1))) unsigned int*)g,
      (__attribute__((address_space(3))) unsigned int*)l, 16, 0, 0);
}

// ---------------------------------------------------------------------------
// Prep: x f32 -> bf16 workspace, both layouts (unchanged, verified).
// ---------------------------------------------------------------------------
__global__ __launch_bounds__(256) void prep_bf16(
    const float* __restrict__ x,
    unsigned short* __restrict__ xbf, unsigned short* __restrict__ xvt)
{
  const int tid = threadIdx.x;
  const int w = tid >> 6, l = tid & 63;
  const int l15 = l & 15, q4 = l >> 4;
  const int bt = (int)blockIdx.x;            // b*128 + t
  const float* xb = x + (size_t)bt * 16 * kD;
  unsigned short* ob = xbf + (size_t)bt * kTileShorts;
  unsigned short* ov = xvt + (size_t)bt * kTileShorts;

#pragma unroll
  for (int it = 0; it < 3; ++it) {
    const int dq = l15 + 16 * it + 48 * w;   // global d-quad index, [0,192)
    unsigned lo[4], hi[4];
#pragma unroll
    for (int jj = 0; jj < 4; ++jj) {
      const float4 f = *(const float4*)(xb + (size_t)(q4 + 4 * jj) * kD + 4 * dq);
      lo[jj] = pk_hi16(FB(f.y), FB(f.x));    // bf16 d+1 | d+0
      hi[jj] = pk_hi16(FB(f.w), FB(f.z));    // bf16 d+3 | d+2
    }
    // ---- xbf: chunked row-major + 16B-group XOR swizzle ----
    const int dp = 4 * (l15 + 16 * it);      // d' within w-chunk, [0,192)
    const int g = dp >> 3, e0 = dp & 7;      // e0 in {0,4}
#pragma unroll
    for (int jj = 0; jj < 4; ++jj) {
      const int j = q4 + 4 * jj;
      uint2 v; v.x = lo[jj]; v.y = hi[jj];
      *(uint2*)&ob[w * 3072 + j * 192 + ((g ^ (j & 7)) << 3) + e0] = v;
    }
    // ---- xvt: VTb blocked transpose ----
    const int jb = (4 * q4) ^ (8 * ((dq >> 2) & 1));
    const int base = dq * 64 + jb;
    uint2 v;
    v.x = pk_lo16(lo[1], lo[0]); v.y = pk_lo16(lo[3], lo[2]);
    *(uint2*)&ov[base + ((0 ^ (dq & 3)) << 4)] = v;
    v.x = pk_hi16(lo[1], lo[0]); v.y = pk_hi16(lo[3], lo[2]);
    *(uint2*)&ov[base + ((1 ^ (dq & 3)) << 4)] = v;
    v.x = pk_lo16(hi[1], hi[0]); v.y = pk_lo16(hi[3], hi[2]);
    *(uint2*)&ov[base + ((2 ^ (dq & 3)) << 4)] = v;
    v.x = pk_hi16(hi[1], hi[0]); v.y = pk_hi16(hi[3], hi[2]);
    *(uint2*)&ov[base + ((3 ^ (dq & 3)) << 4)] = v;
  }
}

// ---------------------------------------------------------------------------
// Main attention kernel. 512 threads = 8 waves, each owning a 96-d chunk.
//   mode 0: light Q-tile (q<32), full KV range, direct final write.
//   mode 1: heavy half-1, raw partial O -> out[..,0:768] + (m,l) -> ml.
//   mode 2: heavy half-2, raw partial O -> out[..,768:1536] + (m,l).
// ---------------------------------------------------------------------------
__global__ __launch_bounds__(512, 4) void attn_mfma6(
    const float* __restrict__ x, const float* __restrict__ mask,
    const unsigned short* __restrict__ xbf,
    const unsigned short* __restrict__ xvt,
    float* __restrict__ out, float* __restrict__ ml)
{
  const int tid = threadIdx.x;
  const int w = tid >> 6, l = tid & 63;    // wave 0..7
  const int l15 = l & 15, q4 = l >> 4;     // 16x16 roles
  const int l31 = l & 31, h2 = l >> 5;     // 32x32 roles
  const int cch = w >> 1, hh = w & 1;      // xbf chunk / half within chunk

  // ---- global LPT block mapping (v5 verbatim): 96 slots/batch ----
  const int bid = (int)blockIdx.x;
  const int b = bid & 7;
  const int s = bid >> 3;                    // 0..95
  int qq, t0, t1, mode;
  if (s < 80) {
    int g = (s * 2) / 5;
    if (g > 31) g = 31;
    while (g < 31 && (2 * (g + 1) + ((g + 2) >> 1)) <= s) ++g;
    while (g > 0 && (2 * g + ((g + 1) >> 1)) > s) --g;
    const int r = s - (2 * g + ((g + 1) >> 1));
    if (r < 2) {                             // heavy half
      qq = 63 - g;                           // 32..63
      const int H = qq + 1;                  // tiles per half
      mode = 1 + r;
      t0 = (r == 0) ? 0 : H;
      t1 = (r == 0) ? H : 2 * H;
    } else {                                 // in-band light
      qq = 31 - (g >> 1);                    // 31..16
      mode = 0; t0 = 0; t1 = 2 * qq + 2;
    }
  } else {                                   // tail lights
    qq = 15 - (s - 80);                      // 15..0
    mode = 0; t0 = 0; t1 = 2 * qq + 2;
  }
  const int i0 = qq << 5;                    // rows i0..i0+31

  const float* xb = x + (size_t)b * kT * kD;
  const float* mrow = mask + (size_t)b * kT;
  const unsigned short* xbfB = xbf + (size_t)b * kTilesPerBatch * kTileShorts;
  const unsigned short* xvtB = xvt + (size_t)b * kTilesPerBatch * kTileShorts;

  __shared__ __attribute__((aligned(16))) float sPart[8][16][36];
  __shared__ __attribute__((aligned(16))) unsigned short Pm[32][16];
  __shared__ __attribute__((aligned(16))) float corrS[32];
  __shared__ __attribute__((aligned(16))) float invlS[32];
  __shared__ __attribute__((aligned(16))) float msk[kT];

  // ---- mask-row preload: wave w stages its own 1KB chunk ----
  gload_lds16((const char*)mrow + 1024 * w + 16 * l, (char*)&msk[256 * w]);

  // ---- K-frag lane offsets (short units), also serve Q-frag loads ----
  int koff[3];
#pragma unroll
  for (int s6 = 0; s6 < 3; ++s6) {
    const int G = (4 * (3 * hh + s6) + q4) ^ (l15 & 7);
    koff[s6] = cch * 3072 + l15 * 192 + G * 8;
  }

  // ---- Q fragments: A[m=l15][k], this wave's 96-d chunk ----
  short8 qf[2][3];
#pragma unroll
  for (int mt = 0; mt < 2; ++mt) {
    const unsigned short* tp = xbfB + (size_t)((i0 >> 4) + mt) * kTileShorts;
#pragma unroll
    for (int s6 = 0; s6 < 3; ++s6)
      qf[mt][s6] = *(const short8*)&tp[koff[s6]];
  }

  // PV B-frag base offset into xvt tile (96-d chunk version)
  const int D0 = 24 * w + (l31 >> 2);
  const int vtb_off0 = D0 * 64 + (((l31 & 3) ^ (D0 & 3)) << 4)
                     + ((8 * h2) ^ (8 * ((l31 >> 4) & 1)));

  // ---- prologue K/V register loads for tile t0 ----
  short8 kb[3], vb[3];
  {
    const unsigned short* kt = xbfB + (size_t)t0 * kTileShorts;
    const unsigned short* vt = xvtB + (size_t)t0 * kTileShorts;
#pragma unroll
    for (int s6 = 0; s6 < 3; ++s6) kb[s6] = *(const short8*)&kt[koff[s6]];
#pragma unroll
    for (int nt = 0; nt < 3; ++nt) vb[nt] = *(const short8*)&vt[vtb_off0 + 512 * nt];
  }

  f32x16 o[3];
#pragma unroll
  for (int nt = 0; nt < 3; ++nt)
#pragma unroll
    for (int e = 0; e < 16; ++e) o[nt][e] = 0.0f;

  float mrun = -INFINITY, lrun = 0.0f;
  const float scale = 0.036084391824351615f;  // 1/sqrt(768)

  // softmax roles: 16 threads/row; this thread handles (row r, col j)
  const int r = tid >> 4, j = tid & 15;
  const int irow = i0 + r;
  const int cst = 4 * (j & 3) + 2 * (j >> 3) + ((j >> 2) & 1);  // jstore col

  __syncthreads();  // one-time full drain: msk/qf/kb/vb all ready

  for (int t = t0; t < t1; ++t) {
    const int j0 = t << 4;

    // ---- QK^T partial over this wave's 96-d chunk ----
    {
      f32x4 sf0, sf1;
#pragma unroll
      for (int e = 0; e < 4; ++e) { sf0[e] = 0.f; sf1[e] = 0.f; }
      __builtin_amdgcn_s_setprio(1);
#pragma unroll
      for (int s6 = 0; s6 < 3; ++s6) {
        sf0 = __builtin_amdgcn_mfma_f32_16x16x32_bf16(qf[0][s6], kb[s6], sf0, 0, 0, 0);
        sf1 = __builtin_amdgcn_mfma_f32_16x16x32_bf16(qf[1][s6], kb[s6], sf1, 0, 0, 0);
      }
      __builtin_amdgcn_s_setprio(0);
      *(f32x4*)&sPart[w][l15][4 * q4]      = sf0;  // [w][j=l15][i-col]
      *(f32x4*)&sPart[w][l15][16 + 4 * q4] = sf1;
    }
    // register-prefetch next K tile (in flight across both barriers)
    if (t + 1 < t1) {
      const unsigned short* kn = xbfB + (size_t)(t + 1) * kTileShorts;
#pragma unroll
      for (int s6 = 0; s6 < 3; ++s6) kb[s6] = *(const short8*)&kn[koff[s6]];
    }
    lds_barrier();  // B1: sPart ready

    // ---- online softmax: thread (r, j) ----
    {
      float ssum = 0.f;
#pragma unroll
      for (int ww = 0; ww < 8; ++ww) ssum += sPart[ww][j][r];
      float a = (j0 + j <= irow) ? ssum * scale : -INFINITY;
      float loc = a;
      loc = fmaxf(loc, __shfl_xor(loc, 1, 64));
      loc = fmaxf(loc, __shfl_xor(loc, 2, 64));
      loc = fmaxf(loc, __shfl_xor(loc, 4, 64));
      loc = fmaxf(loc, __shfl_xor(loc, 8, 64));
      const float mn = fmaxf(mrun, loc);
      const float corr = __expf(mrun - mn);   // first tile: exp(-inf)=0
      const float p = __expf(a - mn);
      float rs = p;
      rs += __shfl_xor(rs, 1, 64);
      rs += __shfl_xor(rs, 2, 64);
      rs += __shfl_xor(rs, 4, 64);
      rs += __shfl_xor(rs, 8, 64);
      lrun = lrun * corr + rs;                // denominator: unmasked
      mrun = mn;
      const float wv = (msk[j0 + j] != 0.f) ? p : 0.f;  // numerator: masked
      Pm[r][cst] = (unsigned short)(FB(wv) >> 16);      // bf16 truncation
      if (j == 0) corrS[r] = corr;
    }
    lds_barrier();  // B2: Pm/corrS ready

    // ---- PV: O += P·V  (32x32x16, k in jstore order on both operands) ----
    {
      float cr[16];
#pragma unroll
      for (int e4 = 0; e4 < 4; ++e4) {
        f32x4 qd = *(const f32x4*)&corrS[8 * e4 + 4 * h2];
#pragma unroll
        for (int ee = 0; ee < 4; ++ee) cr[4 * e4 + ee] = qd[ee];
      }
#pragma unroll
      for (int nt = 0; nt < 3; ++nt)
#pragma unroll
        for (int e = 0; e < 16; ++e) o[nt][e] *= cr[e];
      short8 pa = *(const short8*)&Pm[l31][8 * h2];  // A[m=i=l31][k=js]
      __builtin_amdgcn_s_setprio(1);
#pragma unroll
      for (int nt = 0; nt < 3; ++nt)
        o[nt] = __builtin_amdgcn_mfma_f32_32x32x16_bf16(pa, vb[nt], o[nt], 0, 0, 0);
      __builtin_amdgcn_s_setprio(0);
    }
    // register-prefetch next V tile (covered by next QK+softmax)
    if (t + 1 < t1) {
      const unsigned short* vn = xvtB + (size_t)(t + 1) * kTileShorts;
#pragma unroll
      for (int nt = 0; nt < 3; ++nt) vb[nt] = *(const short8*)&vn[vtb_off0 + 512 * nt];
    }
  }

  // ---- epilogue ----
  if (mode == 0) {
    if (j == 0) invlS[r] = (msk[irow] != 0.f) ? 1.0f / lrun : 0.0f;
    lds_barrier();
    float il[16];
#pragma unroll
    for (int e4 = 0; e4 < 4; ++e4) {
      f32x4 qd = *(const f32x4*)&invlS[8 * e4 + 4 * h2];
#pragma unroll
      for (int ee = 0; ee < 4; ++ee) il[4 * e4 + ee] = qd[ee];
    }
    float* ob = out + (size_t)(b * kT + i0) * (2 * kD);
#pragma unroll
    for (int nt = 0; nt < 3; ++nt) {
      const int col = 96 * w + 32 * nt + l31;
#pragma unroll
      for (int e = 0; e < 16; ++e) {
        const int row = (e & 3) + 8 * (e >> 2) + 4 * h2;  // verified 32x32 C/D layout
        ob[(size_t)row * (2 * kD) + col] = o[nt][e] * il[e];
      }
    }
    // self-hidden half: exact fp32 copy (32 rows x 16 thr/row)
    {
      const int rr = tid >> 4;
      const float* srcr = xb + (size_t)(i0 + rr) * kD;
      float* dstr = ob + (size_t)rr * (2 * kD) + kD;
#pragma unroll
      for (int it = 0; it < 12; ++it) {
        const int d4 = (tid & 15) + 16 * it;
        *(float4*)(dstr + 4 * d4) = *(const float4*)(srcr + 4 * d4);
      }
    }
  } else {
    // heavy half: write raw partial O (no normalization, no row gate)
    float* ob = out + (size_t)(b * kT + i0) * (2 * kD) + ((mode == 2) ? kD : 0);
#pragma unroll
    for (int nt = 0; nt < 3; ++nt) {
      const int col = 96 * w + 32 * nt + l31;
#pragma unroll
      for (int e = 0; e < 16; ++e) {
        const int row = (e & 3) + 8 * (e >> 2) + 4 * h2;
        ob[(size_t)row * (2 * kD) + col] = o[nt][e];
      }
    }
    if (j == 0) {
      const int base = (((b * 32 + (qq - 32)) * 2 + (mode - 1)) * 64);
      ml[base + r]      = mrun;
      ml[base + 32 + r] = lrun;
    }
  }
}

// ---------------------------------------------------------------------------
// Combine: merge the two halves of heavy Q-tiles and restore the self-copy.
// ---------------------------------------------------------------------------
__global__ __launch_bounds__(256) void combine_heavy(
    const float* __restrict__ x, const float* __restrict__ mask,
    const float* __restrict__ ml, float* __restrict__ out)
{
  const int tid = threadIdx.x;
  const int bid = (int)blockIdx.x;     // b*32 + hq
  const int b = bid & 7;
  const int hq = bid >> 3;             // 0..31 -> q = hq+32
  const int i0 = (hq + 32) << 5;
  const float* mrow = mask + (size_t)b * kT;
  const float* mlq = ml + (((size_t)b * 32 + hq) * 2) * 64;

  for (int r = 0; r < 32; ++r) {
    const int i = i0 + r;
    float* orow = out + (size_t)(b * kT + i) * (2 * kD);
    const float* xrow = x + (size_t)(b * kT + i) * kD;
    const float m1 = mlq[r],      l1 = mlq[32 + r];
    const float m2 = mlq[64 + r], l2 = mlq[96 + r];
    const float m = fmaxf(m1, m2);
    const float al = __expf(m1 - m), be = __expf(m2 - m);
    const float lsum = al * l1 + be * l2;
    const float gate = (mrow[i] != 0.f) ? 1.0f / lsum : 0.0f;
    const float ga = gate * al, gb = gate * be;
    if (tid < 192) {
      float4 o1 = *(const float4*)(orow + 4 * tid);
      float4 o2 = *(const float4*)(orow + kD + 4 * tid);
      float4 xv = *(const float4*)(xrow + 4 * tid);
      float4 fo;
      fo.x = ga * o1.x + gb * o2.x;
      fo.y = ga * o1.y + gb * o2.y;
      fo.z = ga * o1.z + gb * o2.z;
      fo.w = ga * o1.w + gb * o2.w;
      *(float4*)(orow + 4 * tid) = fo;          // final attn half
      *(float4*)(orow + kD + 4 * tid) = xv;     // restore self-copy
    }
  }
}

extern "C" void kernel_launch(void* const* d_in, const int* in_sizes, int n_in,
                              void* d_out, int out_size, void* d_ws, size_t ws_size,
                              hipStream_t stream) {
  const float* x    = (const float*)d_in[0];
  const float* mask = (const float*)d_in[1];
  float* out = (float*)d_out;
  unsigned short* xbf = (unsigned short*)d_ws;
  unsigned short* xvt = xbf + (size_t)8 * kTilesPerBatch * kTileShorts;
  float* ml = (float*)(xvt + (size_t)8 * kTilesPerBatch * kTileShorts);
  // workspace use: 2 * 8 * 128 * 12288 * 2B + 8*32*2*64*4B = 50,462,720 B
  prep_bf16<<<dim3(8 * kTilesPerBatch), dim3(256), 0, stream>>>(x, xbf, xvt);
  attn_mfma6<<<dim3(768), dim3(512), 0, stream>>>(x, mask, xbf, xvt, out, ml);
  combine_heavy<<<dim3(256), dim3(256), 0, stream>>>(x, mask, ml, out);
}

// Round 4
// 477.354 us; speedup vs baseline: 1.1324x; 1.1324x over previous
//
#include <hip/hip_runtime.h>
#include <math.h>

// B=8, T=2048, D=768. out[b,i,:768] = masked softmax attn (denominator over ALL
// causal j; sit-mask zeroes numerator only; row gated by mask_i), out[b,i,768:] = x[b,i].
//
// v7: per-lane softmax. QK^T partials stored transposed (sPT[w][i][j]) so each
// lane reads the full 16-j row of its own q-row (i=l31) and runs the entire
// online softmax in registers: no shuffles, no Pm LDS, ONE barrier per tile.
// PV A-frag packed per-lane in natural j order; V workspace layout rebuilt to
// match (vnat[d*16+k] = bf16 V[j=k][d], conflict-free b128 reads).
// Defer-max (exact, THR=0): skip O-rescale when row max doesn't grow.
// v5 split-K LPT mapping, staging choreography, and combine kernel verbatim.
constexpr int kT = 2048;
constexpr int kD = 768;
constexpr int kTileShorts = 16 * kD;       // 12288 shorts per 16-row tile
constexpr int kTilesPerBatch = kT / 16;    // 128

typedef __attribute__((ext_vector_type(8))) short short8;
typedef __attribute__((ext_vector_type(4))) float f32x4;
typedef __attribute__((ext_vector_type(16))) float f32x16;

#define FB(f) __builtin_bit_cast(unsigned, (f))
__device__ __forceinline__ unsigned pk_hi16(unsigned hi, unsigned lo) {
  return __builtin_amdgcn_perm(hi, lo, 0x07060302);  // bf16 truncation pack
}

// Workgroup barrier WITHOUT the vmcnt(0) drain __syncthreads() emits.
__device__ __forceinline__ void lds_barrier() {
  asm volatile("" ::: "memory");
  __builtin_amdgcn_s_waitcnt(0xC07F);   // vmcnt=63, expcnt=7, lgkmcnt=0
  __builtin_amdgcn_s_barrier();
  asm volatile("" ::: "memory");
}

// Direct global->LDS copy, 16B/lane. LDS dest = wave-uniform base + lane*16.
__device__ __forceinline__ void gload_lds16(const void* g, void* l) {
  __builtin_amdgcn_global_load_lds(
      (const __attribute__((address_space(1))) unsigned int*)g,
      (__attribute__((address_space(3))) unsigned int*)l, 16, 0, 0);
}

// ---------------------------------------------------------------------------
// Prep: x f32 -> bf16 workspace.
//   xbf (K/Q layout, unchanged): w*3072 + j*192 + ((g ^ (j&7))<<3) + (dp&7)
//   xvt (V layout, NEW): vnat[d*16 + k] = bf16(V[j=k][d])  (natural j order,
//   16B chunk per (d, k-half) -> PV B-frags read as consecutive 16B slots)
// ---------------------------------------------------------------------------
__global__ __launch_bounds__(256) void prep_bf16b(
    const float* __restrict__ x,
    unsigned short* __restrict__ xbf, unsigned short* __restrict__ xvt)
{
  const int tid = threadIdx.x;
  const int w = tid >> 6, l = tid & 63;
  const int l15 = l & 15, q4 = l >> 4;
  const int bt = (int)blockIdx.x;            // b*128 + t
  const float* xb = x + (size_t)bt * 16 * kD;
  unsigned short* ob = xbf + (size_t)bt * kTileShorts;
  unsigned short* ov = xvt + (size_t)bt * kTileShorts;

  __shared__ float xs[16][772];              // f32 tile for V transpose

#pragma unroll
  for (int it = 0; it < 3; ++it) {
    const int dq = l15 + 16 * it + 48 * w;   // global d-quad index, [0,192)
    unsigned lo[4], hi[4];
#pragma unroll
    for (int jj = 0; jj < 4; ++jj) {
      const int j = q4 + 4 * jj;
      const float4 f = *(const float4*)(xb + (size_t)j * kD + 4 * dq);
      *(float4*)&xs[j][4 * dq] = f;          // stage for V pass
      lo[jj] = pk_hi16(FB(f.y), FB(f.x));    // bf16 d+1 | d+0
      hi[jj] = pk_hi16(FB(f.w), FB(f.z));    // bf16 d+3 | d+2
    }
    // ---- xbf: chunked row-major + 16B-group XOR swizzle (unchanged) ----
    const int dp = 4 * (l15 + 16 * it);      // d' within w-chunk, [0,192)
    const int g = dp >> 3, e0 = dp & 7;      // e0 in {0,4}
#pragma unroll
    for (int jj = 0; jj < 4; ++jj) {
      const int j = q4 + 4 * jj;
      uint2 v; v.x = lo[jj]; v.y = hi[jj];
      *(uint2*)&ob[w * 3072 + j * 192 + ((g ^ (j & 7)) << 3) + e0] = v;
    }
  }
  __syncthreads();

  // ---- vnat: ov[d*16 + k] = bf16(x[j=k][d]); thread -> (d, k-half) chunk ----
#pragma unroll
  for (int cc = 0; cc < 6; ++cc) {
    const int c = tid + 256 * cc;            // 0..1535
    const int d = c >> 1, kh = c & 1;
    uint4 u;
    u.x = pk_hi16(FB(xs[8 * kh + 1][d]), FB(xs[8 * kh + 0][d]));
    u.y = pk_hi16(FB(xs[8 * kh + 3][d]), FB(xs[8 * kh + 2][d]));
    u.z = pk_hi16(FB(xs[8 * kh + 5][d]), FB(xs[8 * kh + 4][d]));
    u.w = pk_hi16(FB(xs[8 * kh + 7][d]), FB(xs[8 * kh + 6][d]));
    *(uint4*)&ov[d * 16 + 8 * kh] = u;       // coalesced 16B stores
  }
}

// ---------------------------------------------------------------------------
// Main attention kernel. 256 threads = 4 waves, each owning a 192-d chunk.
//   mode 0: light Q-tile (q<32), full KV range, direct final write.
//   mode 1: heavy half-1, raw partial O -> out[..,0:768] + (m,l) -> ml.
//   mode 2: heavy half-2, raw partial O -> out[..,768:1536] + (m,l).
// ---------------------------------------------------------------------------
__global__ __launch_bounds__(256, 2) void attn_mfma7(
    const float* __restrict__ x, const float* __restrict__ mask,
    const unsigned short* __restrict__ xbf,
    const unsigned short* __restrict__ xvt,
    float* __restrict__ out, float* __restrict__ ml)
{
  const int tid = threadIdx.x;
  const int w = tid >> 6, l = tid & 63;
  const int l15 = l & 15, q4 = l >> 4;   // 16x16 roles
  const int l31 = l & 31, h2 = l >> 5;   // 32x32 roles

  // ---- global LPT block mapping (v5 verbatim): 96 slots/batch ----
  const int bid = (int)blockIdx.x;
  const int b = bid & 7;
  const int s = bid >> 3;                    // 0..95
  int qq, t0, t1, mode;
  if (s < 80) {
    int g = (s * 2) / 5;
    if (g > 31) g = 31;
    while (g < 31 && (2 * (g + 1) + ((g + 2) >> 1)) <= s) ++g;
    while (g > 0 && (2 * g + ((g + 1) >> 1)) > s) --g;
    const int r = s - (2 * g + ((g + 1) >> 1));
    if (r < 2) {                             // heavy half
      qq = 63 - g;                           // 32..63
      const int H = qq + 1;                  // tiles per half
      mode = 1 + r;
      t0 = (r == 0) ? 0 : H;
      t1 = (r == 0) ? H : 2 * H;
    } else {                                 // in-band light
      qq = 31 - (g >> 1);                    // 31..16
      mode = 0; t0 = 0; t1 = 2 * qq + 2;
    }
  } else {                                   // tail lights
    qq = 15 - (s - 80);                      // 15..0
    mode = 0; t0 = 0; t1 = 2 * qq + 2;
  }
  const int i0 = qq << 5;                    // rows i0..i0+31

  const float* xb = x + (size_t)b * kT * kD;
  const float* mrow = mask + (size_t)b * kT;
  const unsigned short* xbfB = xbf + (size_t)b * kTilesPerBatch * kTileShorts;
  const unsigned short* xvtB = xvt + (size_t)b * kTilesPerBatch * kTileShorts;

  __shared__ unsigned short xKc[12288];                          // K tile
  __shared__ unsigned short VTb[12288];                          // V tile (vnat)
  __shared__ __attribute__((aligned(16))) float sPT[2][4][32][20];  // S^T dbuf
  __shared__ __attribute__((aligned(16))) float corrW[4][32];    // per-wave bcast
  __shared__ __attribute__((aligned(16))) float msk[kT];         // sit-mask row

  // ---- mask-row preload (2 gload/wave, wave-own 2KB chunk) ----
  {
    const char* msrc = (const char*)mrow + 2048 * w;
    char* mdst = (char*)&msk[512 * w];
    gload_lds16(msrc + 16 * l, mdst);
    gload_lds16(msrc + 1024 + 16 * l, mdst + 1024);
  }

  // ---- Q fragments (bf16 direct from xbf): A[m=l15][k=8*q4+e] ----
  short8 qf[2][6];
#pragma unroll
  for (int mt = 0; mt < 2; ++mt) {
    const int tq = (i0 >> 4) + mt;
    const unsigned short* tp = xbfB + (size_t)tq * kTileShorts + w * 3072 + l15 * 192;
#pragma unroll
    for (int s6 = 0; s6 < 6; ++s6)
      qf[mt][s6] = *(const short8*)&tp[((4 * s6 + q4) ^ (l15 & 7)) << 3];
  }

  f32x16 o[6];
#pragma unroll
  for (int nt = 0; nt < 6; ++nt)
#pragma unroll
    for (int e = 0; e < 16; ++e) o[nt][e] = 0.0f;

  float mrun = -INFINITY, lrun = 0.0f;
  const float scale = 0.036084391824351615f;  // 1/sqrt(768)
  const int irow = i0 + l31;                  // this lane's softmax row

  // PV B-frag base: vnat chunk for this wave (d in [192w, 192w+192))
  const int vb_base = 3072 * w + 16 * l31 + 8 * h2;

  // stage helpers: each wave copies exactly the 6144B chunk it alone reads
  auto stageK = [&](int t) {
    const unsigned short* src = xbfB + (size_t)t * kTileShorts + w * 3072 + 8 * l;
    unsigned short* dst = &xKc[w * 3072];
#pragma unroll
    for (int i = 0; i < 6; ++i) gload_lds16(src + 512 * i, dst + 512 * i);
  };
  auto stageV = [&](int t) {
    const unsigned short* src = xvtB + (size_t)t * kTileShorts + w * 3072 + 8 * l;
    unsigned short* dst = &VTb[w * 3072];
#pragma unroll
    for (int i = 0; i < 6; ++i) gload_lds16(src + 512 * i, dst + 512 * i);
  };

  // ---- prologue: stage tile t0, full drain once ----
  stageK(t0);
  stageV(t0);
  asm volatile("s_waitcnt vmcnt(0)" ::: "memory");
  lds_barrier();

  for (int t = t0; t < t1; ++t) {
    const int par = t & 1;
    const int j0 = t << 4;

    if (t > t0) { asm volatile("s_waitcnt vmcnt(6)" ::: "memory"); }  // K(t) in

    // ---- QK^T partial over this wave's 192-d chunk ----
    {
      f32x4 sf0, sf1;
#pragma unroll
      for (int e = 0; e < 4; ++e) { sf0[e] = 0.f; sf1[e] = 0.f; }
      const unsigned short* kbase = &xKc[w * 3072 + l15 * 192];
      __builtin_amdgcn_s_setprio(1);
#pragma unroll
      for (int s6 = 0; s6 < 6; ++s6) {
        short8 kb = *(const short8*)&kbase[((4 * s6 + q4) ^ (l15 & 7)) << 3];
        sf0 = __builtin_amdgcn_mfma_f32_16x16x32_bf16(qf[0][s6], kb, sf0, 0, 0, 0);
        sf1 = __builtin_amdgcn_mfma_f32_16x16x32_bf16(qf[1][s6], kb, sf1, 0, 0, 0);
      }
      __builtin_amdgcn_s_setprio(0);
      // transposed store: sPT[par][w][i][j=l15]
#pragma unroll
      for (int e = 0; e < 4; ++e) {
        sPT[par][w][4 * q4 + e][l15]      = sf0[e];
        sPT[par][w][16 + 4 * q4 + e][l15] = sf1[e];
      }
    }

    // issue next K tile into own chunk (ds ops above complete first)
    if (t + 1 < t1) {
      asm volatile("s_waitcnt lgkmcnt(0)" ::: "memory");
      stageK(t + 1);
    }
    lds_barrier();  // B1: sPT[par] ready (the only barrier per tile)

    // ---- per-lane online softmax for row irow = i0+l31 ----
    short8 pa;
    {
      f32x4 mk[4];
#pragma unroll
      for (int jg = 0; jg < 4; ++jg) mk[jg] = *(const f32x4*)&msk[j0 + 4 * jg];

      float aj[16];
#pragma unroll
      for (int jg = 0; jg < 4; ++jg) {
        f32x4 p0 = *(const f32x4*)&sPT[par][0][l31][4 * jg];
        f32x4 p1 = *(const f32x4*)&sPT[par][1][l31][4 * jg];
        f32x4 p2 = *(const f32x4*)&sPT[par][2][l31][4 * jg];
        f32x4 p3 = *(const f32x4*)&sPT[par][3][l31][4 * jg];
        f32x4 sm = (p0 + p1) + (p2 + p3);
#pragma unroll
        for (int m = 0; m < 4; ++m) {
          const int j = 4 * jg + m;
          aj[j] = (j0 + j <= irow) ? sm[m] * scale : -INFINITY;
        }
      }
      // max tree (15 ops, 4 levels)
      float b8[8], c4[4];
#pragma unroll
      for (int k = 0; k < 8; ++k) b8[k] = fmaxf(aj[2 * k], aj[2 * k + 1]);
#pragma unroll
      for (int k = 0; k < 4; ++k) c4[k] = fmaxf(b8[2 * k], b8[2 * k + 1]);
      const float rowmax = fmaxf(fmaxf(c4[0], c4[1]), fmaxf(c4[2], c4[3]));

      // defer-max (exact): rescale only when some row's max grows
      if (!__all(rowmax <= mrun)) {
        const float mn = fmaxf(mrun, rowmax);
        const float corr = __expf(mrun - mn);   // first tile: exp(-inf)=0
        lrun *= corr;
        mrun = mn;
        corrW[w][l31] = corr;                   // h2 halves write same value
        asm volatile("s_waitcnt lgkmcnt(0)" ::: "memory");
        float cr[16];
#pragma unroll
        for (int e4 = 0; e4 < 4; ++e4) {
          f32x4 qd = *(const f32x4*)&corrW[w][8 * e4 + 4 * h2];
#pragma unroll
          for (int ee = 0; ee < 4; ++ee) cr[4 * e4 + ee] = qd[ee];
        }
#pragma unroll
        for (int nt = 0; nt < 6; ++nt)
#pragma unroll
          for (int e = 0; e < 16; ++e) o[nt][e] *= cr[e];
      }

      float wv[16];
      float r0 = 0.f, r1 = 0.f, r2 = 0.f, r3 = 0.f;
#pragma unroll
      for (int jg = 0; jg < 4; ++jg)
#pragma unroll
        for (int m = 0; m < 4; ++m) {
          const int j = 4 * jg + m;
          const float p = __expf(aj[j] - mrun);
          if (m == 0) r0 += p; else if (m == 1) r1 += p;
          else if (m == 2) r2 += p; else r3 += p;
          wv[j] = (mk[jg][m] != 0.f) ? p : 0.f;   // numerator: masked
        }
      lrun += (r0 + r1) + (r2 + r3);              // denominator: unmasked

      // pack this lane's PV A-frag: k = 8*h2 + e, natural j order
      uint4 ulo, uhi;
      ulo.x = pk_hi16(FB(wv[1]),  FB(wv[0]));
      ulo.y = pk_hi16(FB(wv[3]),  FB(wv[2]));
      ulo.z = pk_hi16(FB(wv[5]),  FB(wv[4]));
      ulo.w = pk_hi16(FB(wv[7]),  FB(wv[6]));
      uhi.x = pk_hi16(FB(wv[9]),  FB(wv[8]));
      uhi.y = pk_hi16(FB(wv[11]), FB(wv[10]));
      uhi.z = pk_hi16(FB(wv[13]), FB(wv[12]));
      uhi.w = pk_hi16(FB(wv[15]), FB(wv[14]));
      uint4 up;
      up.x = h2 ? uhi.x : ulo.x;
      up.y = h2 ? uhi.y : ulo.y;
      up.z = h2 ? uhi.z : ulo.z;
      up.w = h2 ? uhi.w : ulo.w;
      pa = __builtin_bit_cast(short8, up);
    }

    // V(t) arrived (K(t+1) may stay in flight)
    if (t + 1 < t1) { asm volatile("s_waitcnt vmcnt(6)" ::: "memory"); }
    else            { asm volatile("s_waitcnt vmcnt(0)" ::: "memory"); }

    // ---- PV: O += P·V  (32x32x16, k = natural j order on both operands) ----
    {
      __builtin_amdgcn_s_setprio(1);
#pragma unroll
      for (int nt = 0; nt < 6; ++nt) {
        short8 vb = *(const short8*)&VTb[vb_base + 512 * nt];  // B[k=j][n=d]
        o[nt] = __builtin_amdgcn_mfma_f32_32x32x16_bf16(pa, vb, o[nt], 0, 0, 0);
      }
      __builtin_amdgcn_s_setprio(0);
    }

    // issue next V tile into own chunk (vb ds_reads complete first)
    if (t + 1 < t1) {
      asm volatile("s_waitcnt lgkmcnt(0)" ::: "memory");
      stageV(t + 1);
    }
  }

  // ---- epilogue ----
  if (mode == 0) {
    corrW[w][l31] = (msk[irow] != 0.f) ? 1.0f / lrun : 0.0f;  // reuse as invl
    asm volatile("s_waitcnt lgkmcnt(0)" ::: "memory");
    float il[16];
#pragma unroll
    for (int e4 = 0; e4 < 4; ++e4) {
      f32x4 qd = *(const f32x4*)&corrW[w][8 * e4 + 4 * h2];
#pragma unroll
      for (int ee = 0; ee < 4; ++ee) il[4 * e4 + ee] = qd[ee];
    }
    float* ob = out + (size_t)(b * kT + i0) * (2 * kD);
#pragma unroll
    for (int nt = 0; nt < 6; ++nt) {
      const int col = 192 * w + 32 * nt + l31;
#pragma unroll
      for (int e = 0; e < 16; ++e) {
        const int row = (e & 3) + 8 * (e >> 2) + 4 * h2;  // verified 32x32 C/D layout
        ob[(size_t)row * (2 * kD) + col] = o[nt][e] * il[e];
      }
    }
    // self-hidden half: exact fp32 copy
#pragma unroll
    for (int pass = 0; pass < 2; ++pass) {
      const int rr = (tid >> 4) + 16 * pass;
      const float* srcr = xb + (size_t)(i0 + rr) * kD;
      float* dstr = ob + (size_t)rr * (2 * kD) + kD;
#pragma unroll
      for (int it = 0; it < 12; ++it) {
        const int d4 = (tid & 15) + 16 * it;
        *(float4*)(dstr + 4 * d4) = *(const float4*)(srcr + 4 * d4);
      }
    }
  } else {
    // heavy half: write raw partial O (no normalization, no row gate)
    float* ob = out + (size_t)(b * kT + i0) * (2 * kD) + ((mode == 2) ? kD : 0);
#pragma unroll
    for (int nt = 0; nt < 6; ++nt) {
      const int col = 192 * w + 32 * nt + l31;
#pragma unroll
      for (int e = 0; e < 16; ++e) {
        const int row = (e & 3) + 8 * (e >> 2) + 4 * h2;
        ob[(size_t)row * (2 * kD) + col] = o[nt][e];
      }
    }
    if (w == 0 && h2 == 0) {
      const int base = (((b * 32 + (qq - 32)) * 2 + (mode - 1)) * 64);
      ml[base + l31]      = mrun;
      ml[base + 32 + l31] = lrun;
    }
  }
}

// ---------------------------------------------------------------------------
// Combine: merge the two halves of heavy Q-tiles and restore the self-copy.
// ---------------------------------------------------------------------------
__global__ __launch_bounds__(256) void combine_heavy(
    const float* __restrict__ x, const float* __restrict__ mask,
    const float* __restrict__ ml, float* __restrict__ out)
{
  const int tid = threadIdx.x;
  const int bid = (int)blockIdx.x;     // b*32 + hq
  const int b = bid & 7;
  const int hq = bid >> 3;             // 0..31 -> q = hq+32
  const int i0 = (hq + 32) << 5;
  const float* mrow = mask + (size_t)b * kT;
  const float* mlq = ml + (((size_t)b * 32 + hq) * 2) * 64;

  for (int r = 0; r < 32; ++r) {
    const int i = i0 + r;
    float* orow = out + (size_t)(b * kT + i) * (2 * kD);
    const float* xrow = x + (size_t)(b * kT + i) * kD;
    const float m1 = mlq[r],      l1 = mlq[32 + r];
    const float m2 = mlq[64 + r], l2 = mlq[96 + r];
    const float m = fmaxf(m1, m2);
    const float al = __expf(m1 - m), be = __expf(m2 - m);
    const float lsum = al * l1 + be * l2;
    const float gate = (mrow[i] != 0.f) ? 1.0f / lsum : 0.0f;
    const float ga = gate * al, gb = gate * be;
    if (tid < 192) {
      float4 o1 = *(const float4*)(orow + 4 * tid);
      float4 o2 = *(const float4*)(orow + kD + 4 * tid);
      float4 xv = *(const float4*)(xrow + 4 * tid);
      float4 fo;
      fo.x = ga * o1.x + gb * o2.x;
      fo.y = ga * o1.y + gb * o2.y;
      fo.z = ga * o1.z + gb * o2.z;
      fo.w = ga * o1.w + gb * o2.w;
      *(float4*)(orow + 4 * tid) = fo;          // final attn half
      *(float4*)(orow + kD + 4 * tid) = xv;     // restore self-copy
    }
  }
}

extern "C" void kernel_launch(void* const* d_in, const int* in_sizes, int n_in,
                              void* d_out, int out_size, void* d_ws, size_t ws_size,
                              hipStream_t stream) {
  const float* x    = (const float*)d_in[0];
  const float* mask = (const float*)d_in[1];
  float* out = (float*)d_out;
  unsigned short* xbf = (unsigned short*)d_ws;
  unsigned short* xvt = xbf + (size_t)8 * kTilesPerBatch * kTileShorts;
  float* ml = (float*)(xvt + (size_t)8 * kTilesPerBatch * kTileShorts);
  // workspace use: 2 * 8 * 128 * 12288 * 2B + 8*32*2*64*4B = 50,462,720 B
  prep_bf16b<<<dim3(8 * kTilesPerBatch), dim3(256), 0, stream>>>(x, xbf, xvt);
  attn_mfma7<<<dim3(768), dim3(256), 0, stream>>>(x, mask, xbf, xvt, out, ml);
  combine_heavy<<<dim3(256), dim3(256), 0, stream>>>(x, mask, ml, out);
}